// Round 7
// baseline (220.626 us; speedup 1.0000x reference)
//
#include <hip/hip_runtime.h>
#include <hip/hip_bf16.h>

#define BSZ 131072

typedef __bf16 v8bf __attribute__((ext_vector_type(8)));
typedef float f32x4 __attribute__((ext_vector_type(4)));

constexpr int RPB = 64;        // rows per block (weight-reuse optimum)
constexpr int MT  = RPB / 16;  // m-tiles per block
constexpr int NTHREADS = 512;  // 8 waves
constexpr int LDA = 264;       // 256 + 8 pad (528B rows, 16B aligned)

// d_ws layout (bf16 element offsets) — fragment-swizzled weights.
constexpr int OFF_B2T = 0;        // Vw2[n][k]   (256x256) NT=16
constexpr int OFF_U2T = 65536;    // Uw2[n][k]   (256x256) NT=16
constexpr int OFF_B2  = 131072;   // Vw2[k][n]   (256x256) NT=16
constexpr int OFF_B3T = 196608;   // Vw3[n][k]   (256x64)  NT=4
constexpr int OFF_B3  = 212992;   // Vw3[k][n]   (64x256)  NT=16
constexpr int OFF_U3  = 229376;   // Uw3[k] (unused by fused_clf now)
constexpr int OFF_GV  = 233472;   // (unused)
constexpr int OFF_LV1 = 237568;   // Vw1[n][k] k<4 else 0  (32x256)  NT=16
constexpr int OFF_LU1 = 245760;   // Uw1[n][k] k<4 else 0  (32x256)  NT=16
constexpr int WS_ELEMS = 253952;

// 3 VALU + 2 trans: exp2-form tanh. Exact at +-inf, no NaN.
__device__ __forceinline__ float tanhf_fast(float x){
  float e = __builtin_amdgcn_exp2f(x * 2.885390082f);   // exp(2x)
  return __builtin_fmaf(-2.0f, __builtin_amdgcn_rcpf(e + 1.0f), 1.0f);
}

__device__ __forceinline__ __bf16 f2bf(float f){
  unsigned u = __builtin_bit_cast(unsigned, f);
  u += 0x8000u;
  unsigned short h = (unsigned short)(u >> 16);
  return __builtin_bit_cast(__bf16, h);
}

// pack 2 f32 -> 2 bf16 in one instr (RNE)
__device__ __forceinline__ unsigned pk2bf(float lo, float hi){
  unsigned r;
  asm("v_cvt_pk_bf16_f32 %0, %1, %2" : "=v"(r) : "v"(lo), "v"(hi));
  return r;
}
__device__ __forceinline__ float bflo(unsigned u){ return __builtin_bit_cast(float, u << 16); }
__device__ __forceinline__ float bfhi(unsigned u){ return __builtin_bit_cast(float, u & 0xffff0000u); }

// ---- weight pre-swizzle: one thread per bf16 element of ws ----
__global__ void prep_weights(const float* __restrict__ Vw2,
                             const float* __restrict__ Uw2,
                             const float* __restrict__ Vw3,
                             const float* __restrict__ Vw1,
                             const float* __restrict__ Uw1,
                             const float* __restrict__ Uw3,
                             __bf16* __restrict__ ws){
  int e = blockIdx.x * 256 + threadIdx.x;
  if (e >= WS_ELEMS) return;
  int idx, NT, base, mode; const float* W;
  if      (e <  65536){ idx = e;          W = Vw2; mode = 0; NT = 16; base = OFF_B2T; }
  else if (e < 131072){ idx = e - 65536;  W = Uw2; mode = 0; NT = 16; base = OFF_U2T; }
  else if (e < 196608){ idx = e - 131072; W = Vw2; mode = 1; NT = 16; base = OFF_B2;  }
  else if (e < 212992){ idx = e - 196608; W = Vw3; mode = 0; NT = 4;  base = OFF_B3T; }
  else if (e < 229376){ idx = e - 212992; W = Vw3; mode = 1; NT = 16; base = OFF_B3;  }
  else if (e < 233472){ idx = e - 229376; W = Uw3; mode = 2; NT = 1;  base = OFF_U3;  }
  else if (e < 237568){ idx = e - 233472; W = Vw1; mode = 3; NT = 1;  base = OFF_GV;  }
  else if (e < 245760){ idx = e - 237568; W = Vw1; mode = 4; NT = 16; base = OFF_LV1; }
  else                { idx = e - 245760; W = Uw1; mode = 4; NT = 16; base = OFF_LU1; }
  int j = idx & 7, l = (idx >> 3) & 63, f = idx >> 9;
  int nt = f % NT, ks = f / NT;
  int k = ks * 32 + (l >> 4) * 8 + j;
  int n = nt * 16 + (l & 15);
  float v;
  if      (mode == 0) v = W[n * 256 + k];
  else if (mode == 1) v = W[k * 256 + n];
  else if (mode == 2) v = (n == 0) ? W[k] : 0.0f;
  else if (mode == 3) v = (n < 4)  ? W[k * 4 + n] : 0.0f;
  else                v = (k < 4)  ? W[n * 4 + k] : 0.0f;
  ws[base + idx] = f2bf(v);
}

__global__ __launch_bounds__(NTHREADS, 6) void fused_clf(
    const float* __restrict__ x, const float* __restrict__ Vw1f,
    const float* __restrict__ Vb1, const float* __restrict__ Vb2,
    const float* __restrict__ Vb3,
    const float* __restrict__ Ub1, const float* __restrict__ Ub2,
    const float* __restrict__ Ub3, const float* __restrict__ Uw3,
    const __bf16* __restrict__ ws,
    float* __restrict__ out)
{
  // Single activation buffer, time-shared: u1 -> a1 -> a2 -> t2'
  __shared__ alignas(16) __bf16 buf[RPB][LDA];
  __shared__ union alignas(16) S3 {             // r4 (U3/gradV partials) | b3
    __bf16 b3[RPB][72];                         // a3' = a3*(1-a3^2)
    float  r4[8][RPB][4];                       // per-wave reduction partials
  } s3;
  __shared__ alignas(16) float red[RPB][4];
  __shared__ float utile[RPB];

  const int tid  = threadIdx.x;
  const int lane = tid & 63;
  const int wave = tid >> 6;       // 0..7
  const int quad = lane >> 4;
  const int l16  = lane & 15;
  const int row0 = blockIdx.x * RPB;

  // ---- x fragments (K=4 zero-padded to 32), B-operand of swapped MFMA ----
  v8bf xa[MT];
  #pragma unroll
  for (int m = 0; m < MT; m++){
    v8bf z;
    #pragma unroll
    for (int j = 0; j < 8; j++) z[j] = (__bf16)0.0f;
    if (quad == 0){
      float4 xv = ((const float4*)x)[row0 + m*16 + l16];
      z[0] = f2bf(xv.x); z[1] = f2bf(xv.y); z[2] = f2bf(xv.z); z[3] = f2bf(xv.w);
    }
    xa[m] = z;
  }

  // Swapped-operand MFMA: acc = mfma(Wfrag, ActFrag) computes C^T: lane
  // holds features f0..f0+3 (f0 = ntbase + quad*4) of batch row m*16+l16.

  // ---- layer-1 via MFMA (single K-step) ----
  auto layer1m = [&](const __bf16* __restrict__ Bw, const float* __restrict__ bv){
    const v8bf* B = (const v8bf*)Bw;
    v8bf bf0 = B[(wave*2 + 0)*64 + lane];
    v8bf bf1 = B[(wave*2 + 1)*64 + lane];
    f32x4 acc[MT][2];
    #pragma unroll
    for (int m = 0; m < MT; m++){ f32x4 z={0.f,0.f,0.f,0.f}; acc[m][0]=z; acc[m][1]=z; }
    __builtin_amdgcn_s_setprio(1);
    #pragma unroll
    for (int m = 0; m < MT; m++){
      acc[m][0] = __builtin_amdgcn_mfma_f32_16x16x32_bf16(bf0, xa[m], acc[m][0], 0,0,0);
      acc[m][1] = __builtin_amdgcn_mfma_f32_16x16x32_bf16(bf1, xa[m], acc[m][1], 0,0,0);
    }
    __builtin_amdgcn_s_setprio(0);
    #pragma unroll
    for (int nt = 0; nt < 2; nt++){
      const int f0 = (wave*2 + nt)*16 + quad*4;
      f32x4 bvv = ((const f32x4*)bv)[f0 >> 2];
      #pragma unroll
      for (int m = 0; m < MT; m++){
        const int brow = m*16 + l16;
        uint2 pk;
        pk.x = pk2bf(tanhf_fast(acc[m][nt][0] + bvv[0]),
                     tanhf_fast(acc[m][nt][1] + bvv[1]));
        pk.y = pk2bf(tanhf_fast(acc[m][nt][2] + bvv[2]),
                     tanhf_fast(acc[m][nt][3] + bvv[3]));
        *(uint2*)&buf[brow][f0] = pk;
      }
    }
  };

  // ---- U2 with fused U3 dot: u2 never materialized. ----
  auto u2dot = [&](const __bf16* __restrict__ Bw,
                   const float* __restrict__ bias, const float* __restrict__ w3){
    f32x4 acc[MT][2];
    #pragma unroll
    for (int m = 0; m < MT; m++){ f32x4 z={0.f,0.f,0.f,0.f}; acc[m][0]=z; acc[m][1]=z; }
    const v8bf* B = (const v8bf*)Bw;
    __builtin_amdgcn_s_setprio(1);
    #pragma unroll
    for (int kk = 0; kk < 8; kk++){
      v8bf a[MT];
      #pragma unroll
      for (int m = 0; m < MT; m++)
        a[m] = *(const v8bf*)&buf[m*16 + l16][kk*32 + quad*8];
      #pragma unroll
      for (int nt = 0; nt < 2; nt++){
        v8bf bf = B[(kk*16 + wave*2 + nt)*64 + lane];
        #pragma unroll
        for (int m = 0; m < MT; m++)
          acc[m][nt] = __builtin_amdgcn_mfma_f32_16x16x32_bf16(bf, a[m], acc[m][nt], 0,0,0);
      }
    }
    __builtin_amdgcn_s_setprio(0);
    float part[MT];
    #pragma unroll
    for (int m = 0; m < MT; m++) part[m] = 0.f;
    #pragma unroll
    for (int nt = 0; nt < 2; nt++){
      const int f0 = (wave*2 + nt)*16 + quad*4;
      f32x4 bvv = ((const f32x4*)bias)[f0 >> 2];
      f32x4 w3v = ((const f32x4*)w3)[f0 >> 2];
      #pragma unroll
      for (int m = 0; m < MT; m++)
        #pragma unroll
        for (int r = 0; r < 4; r++)
          part[m] = __builtin_fmaf(tanhf_fast(acc[m][nt][r] + bvv[r]), w3v[r], part[m]);
    }
    #pragma unroll
    for (int m = 0; m < MT; m++){
      part[m] += __shfl_xor(part[m], 16);
      part[m] += __shfl_xor(part[m], 32);
    }
    if (quad == 0){
      #pragma unroll
      for (int m = 0; m < MT; m++)
        s3.r4[wave][m*16 + l16][0] = part[m];
    }
  };

  // ========== phase A_U: u1 -> buf ====
  layer1m(ws + OFF_LU1, Ub1);
  __syncthreads();
  // ========== phase B: U2 + fused U3 dot -> r4 partials (buf read only) ====
  u2dot(ws + OFF_U2T, Ub2, Uw3);
  __syncthreads();
  // ========== phase A_V: a1 -> buf; wave 0 finishes u ====
  layer1m(ws + OFF_LV1, Vb1);
  if (tid < RPB){
    float z = Ub3[0];
    #pragma unroll
    for (int w = 0; w < 8; w++) z += s3.r4[w][tid][0];
    float u = tanhf_fast(z) * 20.0f;
    utile[tid] = u;
    out[row0 + tid] = u;
  }
  __syncthreads();

  // ========== phase C: V2 in place — read a1 (MFMA), bar, write a2 ====
  {
    f32x4 acc[MT][2];
    #pragma unroll
    for (int m = 0; m < MT; m++){ f32x4 z={0.f,0.f,0.f,0.f}; acc[m][0]=z; acc[m][1]=z; }
    const v8bf* B = (const v8bf*)(ws + OFF_B2T);
    __builtin_amdgcn_s_setprio(1);
    #pragma unroll
    for (int kk = 0; kk < 8; kk++){
      v8bf a[MT];
      #pragma unroll
      for (int m = 0; m < MT; m++)
        a[m] = *(const v8bf*)&buf[m*16 + l16][kk*32 + quad*8];
      #pragma unroll
      for (int nt = 0; nt < 2; nt++){
        v8bf bf = B[(kk*16 + wave*2 + nt)*64 + lane];
        #pragma unroll
        for (int m = 0; m < MT; m++)
          acc[m][nt] = __builtin_amdgcn_mfma_f32_16x16x32_bf16(bf, a[m], acc[m][nt], 0,0,0);
      }
    }
    __builtin_amdgcn_s_setprio(0);
    __syncthreads();            // all a1 reads complete before overwrite
    #pragma unroll
    for (int nt = 0; nt < 2; nt++){
      const int f0 = (wave*2 + nt)*16 + quad*4;
      f32x4 bvv = ((const f32x4*)Vb2)[f0 >> 2];
      #pragma unroll
      for (int m = 0; m < MT; m++){
        const int brow = m*16 + l16;
        uint2 pk;
        pk.x = pk2bf(tanhf_fast(acc[m][nt][0] + bvv[0]),
                     tanhf_fast(acc[m][nt][1] + bvv[1]));
        pk.y = pk2bf(tanhf_fast(acc[m][nt][2] + bvv[2]),
                     tanhf_fast(acc[m][nt][3] + bvv[3]));
        *(uint2*)&buf[brow][f0] = pk;
      }
    }
  }
  __syncthreads();

  // ========== phase D: z3 = a2 @ Vw3^T; fused V partials; a3' -> s3.b3 ====
  {
    const int mp = wave >> 2;     // 0..1
    const int nt = wave & 3;      // 0..3
    f32x4 acc[2];
    { f32x4 z={0.f,0.f,0.f,0.f}; acc[0]=z; acc[1]=z; }
    const v8bf* B = (const v8bf*)(ws + OFF_B3T);
    __builtin_amdgcn_s_setprio(1);
    #pragma unroll
    for (int kk = 0; kk < 8; kk++){
      v8bf bf = B[(kk*4 + nt)*64 + lane];
      #pragma unroll
      for (int m2 = 0; m2 < 2; m2++){
        v8bf a = *(const v8bf*)&buf[(mp*2 + m2)*16 + l16][kk*32 + quad*8];
        acc[m2] = __builtin_amdgcn_mfma_f32_16x16x32_bf16(bf, a, acc[m2], 0,0,0);
      }
    }
    __builtin_amdgcn_s_setprio(0);
    const int f0 = nt*16 + quad*4;
    f32x4 bvv = ((const f32x4*)Vb3)[f0 >> 2];
    #pragma unroll
    for (int m2 = 0; m2 < 2; m2++){
      const int brow = (mp*2 + m2)*16 + l16;
      float t0 = tanhf_fast(acc[m2][0] + bvv[0]);
      float t1 = tanhf_fast(acc[m2][1] + bvv[1]);
      float t2 = tanhf_fast(acc[m2][2] + bvv[2]);
      float t3 = tanhf_fast(acc[m2][3] + bvv[3]);
      float s0 = t0*t0, s1 = t1*t1, s2 = t2*t2, s3q = t3*t3;
      float sq = (s0 + s1) + (s2 + s3q);
      sq += __shfl_xor(sq, 16);
      sq += __shfl_xor(sq, 32);
      if (quad == 0) red[brow][nt] = sq;
      uint2 pk;
      pk.x = pk2bf(t0*(1.0f - s0), t1*(1.0f - s1));
      pk.y = pk2bf(t2*(1.0f - s2), t3*(1.0f - s3q));
      *(uint2*)&s3.b3[brow][f0] = pk;
    }
  }
  __syncthreads();

  // ========== phase E: t3 = a3' @ Vw3; t2' = t3*(1-a2^2) in place; emit V ==
  // a2 is still in buf (E's MFMA reads only s3.b3); each lane reads its own
  // (brow,f0) b64 slot then overwrites it — lane-exclusive, no race.
  {
    f32x4 acc[MT][2];
    #pragma unroll
    for (int m = 0; m < MT; m++){ f32x4 z={0.f,0.f,0.f,0.f}; acc[m][0]=z; acc[m][1]=z; }
    const v8bf* B = (const v8bf*)(ws + OFF_B3);
    __builtin_amdgcn_s_setprio(1);
    #pragma unroll
    for (int kk = 0; kk < 2; kk++){
      v8bf a[MT];
      #pragma unroll
      for (int m = 0; m < MT; m++)
        a[m] = *(const v8bf*)&s3.b3[m*16 + l16][kk*32 + quad*8];
      #pragma unroll
      for (int nt = 0; nt < 2; nt++){
        v8bf bf = B[(kk*16 + wave*2 + nt)*64 + lane];
        #pragma unroll
        for (int m = 0; m < MT; m++)
          acc[m][nt] = __builtin_amdgcn_mfma_f32_16x16x32_bf16(bf, a[m], acc[m][nt], 0,0,0);
      }
    }
    __builtin_amdgcn_s_setprio(0);
    #pragma unroll
    for (int nt = 0; nt < 2; nt++){
      const int f0 = (wave*2 + nt)*16 + quad*4;
      #pragma unroll
      for (int m = 0; m < MT; m++){
        const int brow = m*16 + l16;
        uint2 old = *(const uint2*)&buf[brow][f0];      // a2 (in place)
        float a0 = bflo(old.x), a1 = bfhi(old.x);
        float c0 = bflo(old.y), c1 = bfhi(old.y);
        uint2 pk;
        pk.x = pk2bf(acc[m][nt][0] * (1.0f - a0*a0),
                     acc[m][nt][1] * (1.0f - a1*a1));
        pk.y = pk2bf(acc[m][nt][2] * (1.0f - c0*c0),
                     acc[m][nt][3] * (1.0f - c1*c1));
        *(uint2*)&buf[brow][f0] = pk;
      }
    }
    if (tid < RPB)
      out[BSZ + row0 + tid] = 0.5f * (red[tid][0] + red[tid][1] + red[tid][2] + red[tid][3]);
  }
  __syncthreads();

  // ========== phase F: s2' = (t2'@Vw2)*(1-a1^2), fused grad_V -> r4 ====
  // (1-a1^2) recomputed from x (dot-4 + tanh) — the Vw1f row needed for the
  // grad_V contraction is the same vector, so one load serves both. No
  // long-lived registers.
  {
    f32x4 acc[MT][2];
    #pragma unroll
    for (int m = 0; m < MT; m++){ f32x4 z={0.f,0.f,0.f,0.f}; acc[m][0]=z; acc[m][1]=z; }
    const v8bf* B = (const v8bf*)(ws + OFF_B2);
    __builtin_amdgcn_s_setprio(1);
    #pragma unroll
    for (int kk = 0; kk < 8; kk++){
      v8bf a[MT];
      #pragma unroll
      for (int m = 0; m < MT; m++)
        a[m] = *(const v8bf*)&buf[m*16 + l16][kk*32 + quad*8];
      #pragma unroll
      for (int nt = 0; nt < 2; nt++){
        v8bf bf = B[(kk*16 + wave*2 + nt)*64 + lane];
        #pragma unroll
        for (int m = 0; m < MT; m++)
          acc[m][nt] = __builtin_amdgcn_mfma_f32_16x16x32_bf16(bf, a[m], acc[m][nt], 0,0,0);
      }
    }
    __builtin_amdgcn_s_setprio(0);
    f32x4 gp[MT];
    #pragma unroll
    for (int m = 0; m < MT; m++){ f32x4 z={0.f,0.f,0.f,0.f}; gp[m]=z; }
    #pragma unroll
    for (int nt = 0; nt < 2; nt++){
      const int f0 = (wave*2 + nt)*16 + quad*4;
      f32x4 bv1 = ((const f32x4*)Vb1)[f0 >> 2];
      f32x4 w0 = ((const f32x4*)Vw1f)[f0 + 0];
      f32x4 w1 = ((const f32x4*)Vw1f)[f0 + 1];
      f32x4 w2 = ((const f32x4*)Vw1f)[f0 + 2];
      f32x4 w3 = ((const f32x4*)Vw1f)[f0 + 3];
      #pragma unroll
      for (int m = 0; m < MT; m++){
        float4 xv = ((const float4*)x)[row0 + m*16 + l16];
        float z0 = w0[0]*xv.x + w0[1]*xv.y + w0[2]*xv.z + w0[3]*xv.w + bv1[0];
        float z1 = w1[0]*xv.x + w1[1]*xv.y + w1[2]*xv.z + w1[3]*xv.w + bv1[1];
        float z2 = w2[0]*xv.x + w2[1]*xv.y + w2[2]*xv.z + w2[3]*xv.w + bv1[2];
        float z3 = w3[0]*xv.x + w3[1]*xv.y + w3[2]*xv.z + w3[3]*xv.w + bv1[3];
        float t0 = tanhf_fast(z0), t1 = tanhf_fast(z1);
        float t2 = tanhf_fast(z2), t3 = tanhf_fast(z3);
        float s0 = acc[m][nt][0] * (1.0f - t0*t0);
        float s1 = acc[m][nt][1] * (1.0f - t1*t1);
        float s2 = acc[m][nt][2] * (1.0f - t2*t2);
        float s3v = acc[m][nt][3] * (1.0f - t3*t3);
        gp[m] += s0*w0 + s1*w1 + s2*w2 + s3v*w3;
      }
    }
    #pragma unroll
    for (int m = 0; m < MT; m++){
      #pragma unroll
      for (int j = 0; j < 4; j++){
        float v = gp[m][j];
        v += __shfl_xor(v, 16);
        v += __shfl_xor(v, 32);
        gp[m][j] = v;
      }
      if (quad == 0)
        *(f32x4*)&s3.r4[wave][m*16 + l16][0] = gp[m];
    }
  }
  __syncthreads();
  // ========== phase H: cross-wave sum ====
  if (tid < RPB*4){
    int b = tid >> 2, k2 = tid & 3;
    float s = 0.f;
    #pragma unroll
    for (int w = 0; w < 8; w++) s += s3.r4[w][b][k2];
    red[b][k2] = s;
  }
  __syncthreads();

  // ========== tail: dynamics + Vdot ====
  if (tid < RPB){
    float4 xv = ((const float4*)x)[row0 + tid];
    float th = xv.y, vv = xv.z, om = xv.w;
    float c, s;
    __sincosf(th, &s, &c);
    float rdc  = __builtin_amdgcn_rcpf(c - 24.7f);
    float rdc2 = __builtin_amdgcn_rcpf(c*c - 24.7f);
    float f2v = (c*(9.8f*s + 11.5f*vv) + 68.4f*vv - 1.2f*om*om*s) * rdc;
    float f3v = (-58.8f*vv*c - 243.5f*vv - s*(208.3f + om*om*c)) * rdc2;
    float g2v = (-1.8f*c - 10.9f) * rdc;
    float g3v = (9.3f*c + 38.6f) * rdc2;
    f32x4 rv = *(const f32x4*)&red[tid][0];
    float Lf = rv[0]*vv + rv[1]*om + rv[2]*f2v + rv[3]*f3v;
    float Lg = rv[2]*g2v + rv[3]*g3v;
    out[2*BSZ + row0 + tid] = Lf + Lg * utile[tid];
  }
}

extern "C" void kernel_launch(void* const* d_in, const int* in_sizes, int n_in,
                              void* d_out, int out_size, void* d_ws, size_t ws_size,
                              hipStream_t stream) {
  const float* x   = (const float*)d_in[0];
  const float* Vw1 = (const float*)d_in[1];
  const float* Vb1 = (const float*)d_in[2];
  const float* Vw2 = (const float*)d_in[3];
  const float* Vb2 = (const float*)d_in[4];
  const float* Vw3 = (const float*)d_in[5];
  const float* Vb3 = (const float*)d_in[6];
  const float* Uw1 = (const float*)d_in[7];
  const float* Ub1 = (const float*)d_in[8];
  const float* Uw2 = (const float*)d_in[9];
  const float* Ub2 = (const float*)d_in[10];
  const float* Uw3 = (const float*)d_in[11];
  const float* Ub3 = (const float*)d_in[12];
  __bf16* ws = (__bf16*)d_ws;
  float* out = (float*)d_out;

  hipLaunchKernelGGL(prep_weights, dim3((WS_ELEMS + 255) / 256), dim3(256), 0, stream,
                     Vw2, Uw2, Vw3, Vw1, Uw1, Uw3, ws);
  hipLaunchKernelGGL(fused_clf, dim3(BSZ / RPB), dim3(NTHREADS), 0, stream,
                     x, Vw1, Vb1, Vb2, Vb3, Ub1, Ub2, Ub3, Uw3, ws, out);
}

// Round 8
// 172.555 us; speedup vs baseline: 1.2786x; 1.2786x over previous
//
#include <hip/hip_runtime.h>
#include <hip/hip_bf16.h>

#define BSZ 131072

typedef __bf16 v8bf __attribute__((ext_vector_type(8)));
typedef float f32x4 __attribute__((ext_vector_type(4)));

constexpr int RPB = 64;        // rows per block (weight-reuse optimum)
constexpr int MT  = RPB / 16;  // m-tiles per block
constexpr int NTHREADS = 512;  // 8 waves
constexpr int LDA = 264;       // 256 + 8 pad (528B rows, 16B aligned)

// d_ws layout (bf16 element offsets) — fragment-swizzled weights.
constexpr int OFF_B2T = 0;        // Vw2[n][k]   (256x256) NT=16
constexpr int OFF_U2T = 65536;    // Uw2[n][k]   (256x256) NT=16
constexpr int OFF_B2  = 131072;   // Vw2[k][n]   (256x256) NT=16
constexpr int OFF_B3T = 196608;   // Vw3[n][k]   (256x64)  NT=4
constexpr int OFF_B3  = 212992;   // Vw3[k][n]   (64x256)  NT=16
constexpr int OFF_U3  = 229376;   // Uw3[k] (unused by fused_clf now)
constexpr int OFF_GV  = 233472;   // (unused)
constexpr int OFF_LV1 = 237568;   // Vw1[n][k] k<4 else 0  (32x256)  NT=16
constexpr int OFF_LU1 = 245760;   // Uw1[n][k] k<4 else 0  (32x256)  NT=16
constexpr int WS_ELEMS = 253952;

// 3 VALU + 2 trans: exp2-form tanh. Exact at +-inf, no NaN.
__device__ __forceinline__ float tanhf_fast(float x){
  float e = __builtin_amdgcn_exp2f(x * 2.885390082f);   // exp(2x)
  return __builtin_fmaf(-2.0f, __builtin_amdgcn_rcpf(e + 1.0f), 1.0f);
}

__device__ __forceinline__ __bf16 f2bf(float f){
  unsigned u = __builtin_bit_cast(unsigned, f);
  u += 0x8000u;
  unsigned short h = (unsigned short)(u >> 16);
  return __builtin_bit_cast(__bf16, h);
}

// pack 2 f32 -> 2 bf16 in one instr (RNE)
__device__ __forceinline__ unsigned pk2bf(float lo, float hi){
  unsigned r;
  asm("v_cvt_pk_bf16_f32 %0, %1, %2" : "=v"(r) : "v"(lo), "v"(hi));
  return r;
}
__device__ __forceinline__ float bflo(unsigned u){ return __builtin_bit_cast(float, u << 16); }
__device__ __forceinline__ float bfhi(unsigned u){ return __builtin_bit_cast(float, u & 0xffff0000u); }

// ---- weight pre-swizzle: one thread per bf16 element of ws ----
__global__ void prep_weights(const float* __restrict__ Vw2,
                             const float* __restrict__ Uw2,
                             const float* __restrict__ Vw3,
                             const float* __restrict__ Vw1,
                             const float* __restrict__ Uw1,
                             const float* __restrict__ Uw3,
                             __bf16* __restrict__ ws){
  int e = blockIdx.x * 256 + threadIdx.x;
  if (e >= WS_ELEMS) return;
  int idx, NT, base, mode; const float* W;
  if      (e <  65536){ idx = e;          W = Vw2; mode = 0; NT = 16; base = OFF_B2T; }
  else if (e < 131072){ idx = e - 65536;  W = Uw2; mode = 0; NT = 16; base = OFF_U2T; }
  else if (e < 196608){ idx = e - 131072; W = Vw2; mode = 1; NT = 16; base = OFF_B2;  }
  else if (e < 212992){ idx = e - 196608; W = Vw3; mode = 0; NT = 4;  base = OFF_B3T; }
  else if (e < 229376){ idx = e - 212992; W = Vw3; mode = 1; NT = 16; base = OFF_B3;  }
  else if (e < 233472){ idx = e - 229376; W = Uw3; mode = 2; NT = 1;  base = OFF_U3;  }
  else if (e < 237568){ idx = e - 233472; W = Vw1; mode = 3; NT = 1;  base = OFF_GV;  }
  else if (e < 245760){ idx = e - 237568; W = Vw1; mode = 4; NT = 16; base = OFF_LV1; }
  else                { idx = e - 245760; W = Uw1; mode = 4; NT = 16; base = OFF_LU1; }
  int j = idx & 7, l = (idx >> 3) & 63, f = idx >> 9;
  int nt = f % NT, ks = f / NT;
  int k = ks * 32 + (l >> 4) * 8 + j;
  int n = nt * 16 + (l & 15);
  float v;
  if      (mode == 0) v = W[n * 256 + k];
  else if (mode == 1) v = W[k * 256 + n];
  else if (mode == 2) v = (n == 0) ? W[k] : 0.0f;
  else if (mode == 3) v = (n < 4)  ? W[k * 4 + n] : 0.0f;
  else                v = (k < 4)  ? W[n * 4 + k] : 0.0f;
  ws[base + idx] = f2bf(v);
}

// launch_bounds (512,4): 128-reg budget — proven spill-free (r2/r5: 56 VGPR).
// Actual occupancy = min(LDS: 44.5KB -> 3 blocks/CU, VGPR: 56 -> 8 w/SIMD)
// = 3 blocks/CU. The (512,6) 85-reg cap spilled ~190MB scratch (r6/r7).
__global__ __launch_bounds__(NTHREADS, 4) void fused_clf(
    const float* __restrict__ x, const float* __restrict__ Vw1f,
    const float* __restrict__ Vb1, const float* __restrict__ Vb2,
    const float* __restrict__ Vb3,
    const float* __restrict__ Ub1, const float* __restrict__ Ub2,
    const float* __restrict__ Ub3, const float* __restrict__ Uw3,
    const __bf16* __restrict__ ws,
    float* __restrict__ out)
{
  // Single activation buffer, time-shared: u1 -> a1 -> a2 -> t2'
  __shared__ alignas(16) __bf16 buf[RPB][LDA];
  __shared__ union alignas(16) S3 {             // r4 (U3/gradV partials) | b3
    __bf16 b3[RPB][72];                         // a3' = a3*(1-a3^2)
    float  r4[8][RPB][4];                       // per-wave reduction partials
  } s3;
  __shared__ alignas(16) float red[RPB][4];
  __shared__ float utile[RPB];

  const int tid  = threadIdx.x;
  const int lane = tid & 63;
  const int wave = tid >> 6;       // 0..7
  const int quad = lane >> 4;
  const int l16  = lane & 15;
  const int row0 = blockIdx.x * RPB;

  // ---- x fragments (K=4 zero-padded to 32), B-operand of swapped MFMA ----
  v8bf xa[MT];
  #pragma unroll
  for (int m = 0; m < MT; m++){
    v8bf z;
    #pragma unroll
    for (int j = 0; j < 8; j++) z[j] = (__bf16)0.0f;
    if (quad == 0){
      float4 xv = ((const float4*)x)[row0 + m*16 + l16];
      z[0] = f2bf(xv.x); z[1] = f2bf(xv.y); z[2] = f2bf(xv.z); z[3] = f2bf(xv.w);
    }
    xa[m] = z;
  }

  // Swapped-operand MFMA: acc = mfma(Wfrag, ActFrag) computes C^T: lane
  // holds features f0..f0+3 (f0 = ntbase + quad*4) of batch row m*16+l16.

  // ---- layer-1 via MFMA (single K-step) ----
  auto layer1m = [&](const __bf16* __restrict__ Bw, const float* __restrict__ bv){
    const v8bf* B = (const v8bf*)Bw;
    v8bf bf0 = B[(wave*2 + 0)*64 + lane];
    v8bf bf1 = B[(wave*2 + 1)*64 + lane];
    f32x4 acc[MT][2];
    #pragma unroll
    for (int m = 0; m < MT; m++){ f32x4 z={0.f,0.f,0.f,0.f}; acc[m][0]=z; acc[m][1]=z; }
    __builtin_amdgcn_s_setprio(1);
    #pragma unroll
    for (int m = 0; m < MT; m++){
      acc[m][0] = __builtin_amdgcn_mfma_f32_16x16x32_bf16(bf0, xa[m], acc[m][0], 0,0,0);
      acc[m][1] = __builtin_amdgcn_mfma_f32_16x16x32_bf16(bf1, xa[m], acc[m][1], 0,0,0);
    }
    __builtin_amdgcn_s_setprio(0);
    #pragma unroll
    for (int nt = 0; nt < 2; nt++){
      const int f0 = (wave*2 + nt)*16 + quad*4;
      f32x4 bvv = ((const f32x4*)bv)[f0 >> 2];
      #pragma unroll
      for (int m = 0; m < MT; m++){
        const int brow = m*16 + l16;
        uint2 pk;
        pk.x = pk2bf(tanhf_fast(acc[m][nt][0] + bvv[0]),
                     tanhf_fast(acc[m][nt][1] + bvv[1]));
        pk.y = pk2bf(tanhf_fast(acc[m][nt][2] + bvv[2]),
                     tanhf_fast(acc[m][nt][3] + bvv[3]));
        *(uint2*)&buf[brow][f0] = pk;
      }
    }
  };

  // ---- U2 with fused U3 dot: u2 never materialized. ----
  auto u2dot = [&](const __bf16* __restrict__ Bw,
                   const float* __restrict__ bias, const float* __restrict__ w3){
    f32x4 acc[MT][2];
    #pragma unroll
    for (int m = 0; m < MT; m++){ f32x4 z={0.f,0.f,0.f,0.f}; acc[m][0]=z; acc[m][1]=z; }
    const v8bf* B = (const v8bf*)Bw;
    __builtin_amdgcn_s_setprio(1);
    #pragma unroll
    for (int kk = 0; kk < 8; kk++){
      v8bf a[MT];
      #pragma unroll
      for (int m = 0; m < MT; m++)
        a[m] = *(const v8bf*)&buf[m*16 + l16][kk*32 + quad*8];
      #pragma unroll
      for (int nt = 0; nt < 2; nt++){
        v8bf bf = B[(kk*16 + wave*2 + nt)*64 + lane];
        #pragma unroll
        for (int m = 0; m < MT; m++)
          acc[m][nt] = __builtin_amdgcn_mfma_f32_16x16x32_bf16(bf, a[m], acc[m][nt], 0,0,0);
      }
    }
    __builtin_amdgcn_s_setprio(0);
    float part[MT];
    #pragma unroll
    for (int m = 0; m < MT; m++) part[m] = 0.f;
    #pragma unroll
    for (int nt = 0; nt < 2; nt++){
      const int f0 = (wave*2 + nt)*16 + quad*4;
      f32x4 bvv = ((const f32x4*)bias)[f0 >> 2];
      f32x4 w3v = ((const f32x4*)w3)[f0 >> 2];
      #pragma unroll
      for (int m = 0; m < MT; m++)
        #pragma unroll
        for (int r = 0; r < 4; r++)
          part[m] = __builtin_fmaf(tanhf_fast(acc[m][nt][r] + bvv[r]), w3v[r], part[m]);
    }
    #pragma unroll
    for (int m = 0; m < MT; m++){
      part[m] += __shfl_xor(part[m], 16);
      part[m] += __shfl_xor(part[m], 32);
    }
    if (quad == 0){
      #pragma unroll
      for (int m = 0; m < MT; m++)
        s3.r4[wave][m*16 + l16][0] = part[m];
    }
  };

  // ========== phase A_U: u1 -> buf ====
  layer1m(ws + OFF_LU1, Ub1);
  __syncthreads();
  // ========== phase B: U2 + fused U3 dot -> r4 partials (buf read only) ====
  u2dot(ws + OFF_U2T, Ub2, Uw3);
  __syncthreads();
  // ========== phase A_V: a1 -> buf; wave 0 finishes u ====
  layer1m(ws + OFF_LV1, Vb1);
  if (tid < RPB){
    float z = Ub3[0];
    #pragma unroll
    for (int w = 0; w < 8; w++) z += s3.r4[w][tid][0];
    float u = tanhf_fast(z) * 20.0f;
    utile[tid] = u;
    out[row0 + tid] = u;
  }
  __syncthreads();

  // ========== phase C: V2 in place — read a1 (MFMA), bar, write a2 ====
  {
    f32x4 acc[MT][2];
    #pragma unroll
    for (int m = 0; m < MT; m++){ f32x4 z={0.f,0.f,0.f,0.f}; acc[m][0]=z; acc[m][1]=z; }
    const v8bf* B = (const v8bf*)(ws + OFF_B2T);
    __builtin_amdgcn_s_setprio(1);
    #pragma unroll
    for (int kk = 0; kk < 8; kk++){
      v8bf a[MT];
      #pragma unroll
      for (int m = 0; m < MT; m++)
        a[m] = *(const v8bf*)&buf[m*16 + l16][kk*32 + quad*8];
      #pragma unroll
      for (int nt = 0; nt < 2; nt++){
        v8bf bf = B[(kk*16 + wave*2 + nt)*64 + lane];
        #pragma unroll
        for (int m = 0; m < MT; m++)
          acc[m][nt] = __builtin_amdgcn_mfma_f32_16x16x32_bf16(bf, a[m], acc[m][nt], 0,0,0);
      }
    }
    __builtin_amdgcn_s_setprio(0);
    __syncthreads();            // all a1 reads complete before overwrite
    #pragma unroll
    for (int nt = 0; nt < 2; nt++){
      const int f0 = (wave*2 + nt)*16 + quad*4;
      f32x4 bvv = ((const f32x4*)Vb2)[f0 >> 2];
      #pragma unroll
      for (int m = 0; m < MT; m++){
        const int brow = m*16 + l16;
        uint2 pk;
        pk.x = pk2bf(tanhf_fast(acc[m][nt][0] + bvv[0]),
                     tanhf_fast(acc[m][nt][1] + bvv[1]));
        pk.y = pk2bf(tanhf_fast(acc[m][nt][2] + bvv[2]),
                     tanhf_fast(acc[m][nt][3] + bvv[3]));
        *(uint2*)&buf[brow][f0] = pk;
      }
    }
  }
  __syncthreads();

  // ========== phase D: z3 = a2 @ Vw3^T; fused V partials; a3' -> s3.b3 ====
  {
    const int mp = wave >> 2;     // 0..1
    const int nt = wave & 3;      // 0..3
    f32x4 acc[2];
    { f32x4 z={0.f,0.f,0.f,0.f}; acc[0]=z; acc[1]=z; }
    const v8bf* B = (const v8bf*)(ws + OFF_B3T);
    __builtin_amdgcn_s_setprio(1);
    #pragma unroll
    for (int kk = 0; kk < 8; kk++){
      v8bf bf = B[(kk*4 + nt)*64 + lane];
      #pragma unroll
      for (int m2 = 0; m2 < 2; m2++){
        v8bf a = *(const v8bf*)&buf[(mp*2 + m2)*16 + l16][kk*32 + quad*8];
        acc[m2] = __builtin_amdgcn_mfma_f32_16x16x32_bf16(bf, a, acc[m2], 0,0,0);
      }
    }
    __builtin_amdgcn_s_setprio(0);
    const int f0 = nt*16 + quad*4;
    f32x4 bvv = ((const f32x4*)Vb3)[f0 >> 2];
    #pragma unroll
    for (int m2 = 0; m2 < 2; m2++){
      const int brow = (mp*2 + m2)*16 + l16;
      float t0 = tanhf_fast(acc[m2][0] + bvv[0]);
      float t1 = tanhf_fast(acc[m2][1] + bvv[1]);
      float t2 = tanhf_fast(acc[m2][2] + bvv[2]);
      float t3 = tanhf_fast(acc[m2][3] + bvv[3]);
      float s0 = t0*t0, s1 = t1*t1, s2 = t2*t2, s3q = t3*t3;
      float sq = (s0 + s1) + (s2 + s3q);
      sq += __shfl_xor(sq, 16);
      sq += __shfl_xor(sq, 32);
      if (quad == 0) red[brow][nt] = sq;
      uint2 pk;
      pk.x = pk2bf(t0*(1.0f - s0), t1*(1.0f - s1));
      pk.y = pk2bf(t2*(1.0f - s2), t3*(1.0f - s3q));
      *(uint2*)&s3.b3[brow][f0] = pk;
    }
  }
  __syncthreads();

  // ========== phase E: t3 = a3' @ Vw3; t2' = t3*(1-a2^2) in place; emit V ==
  // a2 is still in buf (E's MFMA reads only s3.b3); each lane reads its own
  // (brow,f0) b64 slot then overwrites it — lane-exclusive, no race.
  {
    f32x4 acc[MT][2];
    #pragma unroll
    for (int m = 0; m < MT; m++){ f32x4 z={0.f,0.f,0.f,0.f}; acc[m][0]=z; acc[m][1]=z; }
    const v8bf* B = (const v8bf*)(ws + OFF_B3);
    __builtin_amdgcn_s_setprio(1);
    #pragma unroll
    for (int kk = 0; kk < 2; kk++){
      v8bf a[MT];
      #pragma unroll
      for (int m = 0; m < MT; m++)
        a[m] = *(const v8bf*)&s3.b3[m*16 + l16][kk*32 + quad*8];
      #pragma unroll
      for (int nt = 0; nt < 2; nt++){
        v8bf bf = B[(kk*16 + wave*2 + nt)*64 + lane];
        #pragma unroll
        for (int m = 0; m < MT; m++)
          acc[m][nt] = __builtin_amdgcn_mfma_f32_16x16x32_bf16(bf, a[m], acc[m][nt], 0,0,0);
      }
    }
    __builtin_amdgcn_s_setprio(0);
    #pragma unroll
    for (int nt = 0; nt < 2; nt++){
      const int f0 = (wave*2 + nt)*16 + quad*4;
      #pragma unroll
      for (int m = 0; m < MT; m++){
        const int brow = m*16 + l16;
        uint2 old = *(const uint2*)&buf[brow][f0];      // a2 (in place)
        float a0 = bflo(old.x), a1 = bfhi(old.x);
        float c0 = bflo(old.y), c1 = bfhi(old.y);
        uint2 pk;
        pk.x = pk2bf(acc[m][nt][0] * (1.0f - a0*a0),
                     acc[m][nt][1] * (1.0f - a1*a1));
        pk.y = pk2bf(acc[m][nt][2] * (1.0f - c0*c0),
                     acc[m][nt][3] * (1.0f - c1*c1));
        *(uint2*)&buf[brow][f0] = pk;
      }
    }
    if (tid < RPB)
      out[BSZ + row0 + tid] = 0.5f * (red[tid][0] + red[tid][1] + red[tid][2] + red[tid][3]);
  }
  __syncthreads();

  // ========== phase F: s2' = (t2'@Vw2)*(1-a1^2), fused grad_V -> r4 ====
  // (1-a1^2) recomputed from x (dot-4 + tanh) — the Vw1f row needed for the
  // grad_V contraction is the same vector, so one load serves both. No
  // long-lived registers.
  {
    f32x4 acc[MT][2];
    #pragma unroll
    for (int m = 0; m < MT; m++){ f32x4 z={0.f,0.f,0.f,0.f}; acc[m][0]=z; acc[m][1]=z; }
    const v8bf* B = (const v8bf*)(ws + OFF_B2);
    __builtin_amdgcn_s_setprio(1);
    #pragma unroll
    for (int kk = 0; kk < 8; kk++){
      v8bf a[MT];
      #pragma unroll
      for (int m = 0; m < MT; m++)
        a[m] = *(const v8bf*)&buf[m*16 + l16][kk*32 + quad*8];
      #pragma unroll
      for (int nt = 0; nt < 2; nt++){
        v8bf bf = B[(kk*16 + wave*2 + nt)*64 + lane];
        #pragma unroll
        for (int m = 0; m < MT; m++)
          acc[m][nt] = __builtin_amdgcn_mfma_f32_16x16x32_bf16(bf, a[m], acc[m][nt], 0,0,0);
      }
    }
    __builtin_amdgcn_s_setprio(0);
    f32x4 gp[MT];
    #pragma unroll
    for (int m = 0; m < MT; m++){ f32x4 z={0.f,0.f,0.f,0.f}; gp[m]=z; }
    #pragma unroll
    for (int nt = 0; nt < 2; nt++){
      const int f0 = (wave*2 + nt)*16 + quad*4;
      f32x4 bv1 = ((const f32x4*)Vb1)[f0 >> 2];
      f32x4 w0 = ((const f32x4*)Vw1f)[f0 + 0];
      f32x4 w1 = ((const f32x4*)Vw1f)[f0 + 1];
      f32x4 w2 = ((const f32x4*)Vw1f)[f0 + 2];
      f32x4 w3 = ((const f32x4*)Vw1f)[f0 + 3];
      #pragma unroll
      for (int m = 0; m < MT; m++){
        float4 xv = ((const float4*)x)[row0 + m*16 + l16];
        float z0 = w0[0]*xv.x + w0[1]*xv.y + w0[2]*xv.z + w0[3]*xv.w + bv1[0];
        float z1 = w1[0]*xv.x + w1[1]*xv.y + w1[2]*xv.z + w1[3]*xv.w + bv1[1];
        float z2 = w2[0]*xv.x + w2[1]*xv.y + w2[2]*xv.z + w2[3]*xv.w + bv1[2];
        float z3 = w3[0]*xv.x + w3[1]*xv.y + w3[2]*xv.z + w3[3]*xv.w + bv1[3];
        float t0 = tanhf_fast(z0), t1 = tanhf_fast(z1);
        float t2 = tanhf_fast(z2), t3 = tanhf_fast(z3);
        float s0 = acc[m][nt][0] * (1.0f - t0*t0);
        float s1 = acc[m][nt][1] * (1.0f - t1*t1);
        float s2 = acc[m][nt][2] * (1.0f - t2*t2);
        float s3v = acc[m][nt][3] * (1.0f - t3*t3);
        gp[m] += s0*w0 + s1*w1 + s2*w2 + s3v*w3;
      }
    }
    #pragma unroll
    for (int m = 0; m < MT; m++){
      #pragma unroll
      for (int j = 0; j < 4; j++){
        float v = gp[m][j];
        v += __shfl_xor(v, 16);
        v += __shfl_xor(v, 32);
        gp[m][j] = v;
      }
      if (quad == 0)
        *(f32x4*)&s3.r4[wave][m*16 + l16][0] = gp[m];
    }
  }
  __syncthreads();
  // ========== phase H: cross-wave sum ====
  if (tid < RPB*4){
    int b = tid >> 2, k2 = tid & 3;
    float s = 0.f;
    #pragma unroll
    for (int w = 0; w < 8; w++) s += s3.r4[w][b][k2];
    red[b][k2] = s;
  }
  __syncthreads();

  // ========== tail: dynamics + Vdot ====
  if (tid < RPB){
    float4 xv = ((const float4*)x)[row0 + tid];
    float th = xv.y, vv = xv.z, om = xv.w;
    float c, s;
    __sincosf(th, &s, &c);
    float rdc  = __builtin_amdgcn_rcpf(c - 24.7f);
    float rdc2 = __builtin_amdgcn_rcpf(c*c - 24.7f);
    float f2v = (c*(9.8f*s + 11.5f*vv) + 68.4f*vv - 1.2f*om*om*s) * rdc;
    float f3v = (-58.8f*vv*c - 243.5f*vv - s*(208.3f + om*om*c)) * rdc2;
    float g2v = (-1.8f*c - 10.9f) * rdc;
    float g3v = (9.3f*c + 38.6f) * rdc2;
    f32x4 rv = *(const f32x4*)&red[tid][0];
    float Lf = rv[0]*vv + rv[1]*om + rv[2]*f2v + rv[3]*f3v;
    float Lg = rv[2]*g2v + rv[3]*g3v;
    out[2*BSZ + row0 + tid] = Lf + Lg * utile[tid];
  }
}

extern "C" void kernel_launch(void* const* d_in, const int* in_sizes, int n_in,
                              void* d_out, int out_size, void* d_ws, size_t ws_size,
                              hipStream_t stream) {
  const float* x   = (const float*)d_in[0];
  const float* Vw1 = (const float*)d_in[1];
  const float* Vb1 = (const float*)d_in[2];
  const float* Vw2 = (const float*)d_in[3];
  const float* Vb2 = (const float*)d_in[4];
  const float* Vw3 = (const float*)d_in[5];
  const float* Vb3 = (const float*)d_in[6];
  const float* Uw1 = (const float*)d_in[7];
  const float* Ub1 = (const float*)d_in[8];
  const float* Uw2 = (const float*)d_in[9];
  const float* Ub2 = (const float*)d_in[10];
  const float* Uw3 = (const float*)d_in[11];
  const float* Ub3 = (const float*)d_in[12];
  __bf16* ws = (__bf16*)d_ws;
  float* out = (float*)d_out;

  hipLaunchKernelGGL(prep_weights, dim3((WS_ELEMS + 255) / 256), dim3(256), 0, stream,
                     Vw2, Uw2, Vw3, Vw1, Uw1, Uw3, ws);
  hipLaunchKernelGGL(fused_clf, dim3(BSZ / RPB), dim3(NTHREADS), 0, stream,
                     x, Vw1, Vb1, Vb2, Vb3, Ub1, Ub2, Ub3, Uw3, ws, out);
}

// Round 9
// 171.917 us; speedup vs baseline: 1.2833x; 1.0037x over previous
//
#include <hip/hip_runtime.h>
#include <hip/hip_bf16.h>

#define BSZ 131072

typedef __bf16 v8bf __attribute__((ext_vector_type(8)));
typedef float f32x4 __attribute__((ext_vector_type(4)));

constexpr int RPB = 64;        // rows per block (weight-reuse optimum)
constexpr int MT  = RPB / 16;  // m-tiles per block
constexpr int NTHREADS = 512;  // 8 waves
constexpr int LDA = 264;       // 256 + 8 pad (528B rows, 16B aligned)

// d_ws layout (bf16 element offsets) — fragment-swizzled weights.
constexpr int OFF_B2T = 0;        // Vw2[n][k]   (256x256) NT=16
constexpr int OFF_U2T = 65536;    // Uw2[n][k]   (256x256) NT=16
constexpr int OFF_B2  = 131072;   // Vw2[k][n]   (256x256) NT=16
constexpr int OFF_B3T = 196608;   // Vw3[n][k]   (256x64)  NT=4
constexpr int OFF_B3  = 212992;   // Vw3[k][n]   (64x256)  NT=16
constexpr int OFF_U3  = 229376;   // (unused by fused_clf)
constexpr int OFF_GV  = 233472;   // (unused)
constexpr int OFF_LV1 = 237568;   // Vw1[n][k] k<4 else 0  (32x256)  NT=16
constexpr int OFF_LU1 = 245760;   // Uw1[n][k] k<4 else 0  (32x256)  NT=16
constexpr int WS_ELEMS = 253952;

// 3 VALU + 2 trans: exp2-form tanh. Exact at +-inf, no NaN.
__device__ __forceinline__ float tanhf_fast(float x){
  float e = __builtin_amdgcn_exp2f(x * 2.885390082f);   // exp(2x)
  return __builtin_fmaf(-2.0f, __builtin_amdgcn_rcpf(e + 1.0f), 1.0f);
}

__device__ __forceinline__ __bf16 f2bf(float f){
  unsigned u = __builtin_bit_cast(unsigned, f);
  u += 0x8000u;
  unsigned short h = (unsigned short)(u >> 16);
  return __builtin_bit_cast(__bf16, h);
}

// pack 2 f32 -> 2 bf16 in one instr (RNE)
__device__ __forceinline__ unsigned pk2bf(float lo, float hi){
  unsigned r;
  asm("v_cvt_pk_bf16_f32 %0, %1, %2" : "=v"(r) : "v"(lo), "v"(hi));
  return r;
}
__device__ __forceinline__ float bflo(unsigned u){ return __builtin_bit_cast(float, u << 16); }
__device__ __forceinline__ float bfhi(unsigned u){ return __builtin_bit_cast(float, u & 0xffff0000u); }

// ---- weight pre-swizzle: one thread per bf16 element of ws ----
__global__ void prep_weights(const float* __restrict__ Vw2,
                             const float* __restrict__ Uw2,
                             const float* __restrict__ Vw3,
                             const float* __restrict__ Vw1,
                             const float* __restrict__ Uw1,
                             const float* __restrict__ Uw3,
                             __bf16* __restrict__ ws){
  int e = blockIdx.x * 256 + threadIdx.x;
  if (e >= WS_ELEMS) return;
  int idx, NT, base, mode; const float* W;
  if      (e <  65536){ idx = e;          W = Vw2; mode = 0; NT = 16; base = OFF_B2T; }
  else if (e < 131072){ idx = e - 65536;  W = Uw2; mode = 0; NT = 16; base = OFF_U2T; }
  else if (e < 196608){ idx = e - 131072; W = Vw2; mode = 1; NT = 16; base = OFF_B2;  }
  else if (e < 212992){ idx = e - 196608; W = Vw3; mode = 0; NT = 4;  base = OFF_B3T; }
  else if (e < 229376){ idx = e - 212992; W = Vw3; mode = 1; NT = 16; base = OFF_B3;  }
  else if (e < 233472){ idx = e - 229376; W = Uw3; mode = 2; NT = 1;  base = OFF_U3;  }
  else if (e < 237568){ idx = e - 233472; W = Vw1; mode = 3; NT = 1;  base = OFF_GV;  }
  else if (e < 245760){ idx = e - 237568; W = Vw1; mode = 4; NT = 16; base = OFF_LV1; }
  else                { idx = e - 245760; W = Uw1; mode = 4; NT = 16; base = OFF_LU1; }
  int j = idx & 7, l = (idx >> 3) & 63, f = idx >> 9;
  int nt = f % NT, ks = f / NT;
  int k = ks * 32 + (l >> 4) * 8 + j;
  int n = nt * 16 + (l & 15);
  float v;
  if      (mode == 0) v = W[n * 256 + k];
  else if (mode == 1) v = W[k * 256 + n];
  else if (mode == 2) v = (n == 0) ? W[k] : 0.0f;
  else if (mode == 3) v = (n < 4)  ? W[k * 4 + n] : 0.0f;
  else                v = (k < 4)  ? W[n * 4 + k] : 0.0f;
  ws[base + idx] = f2bf(v);
}

// (512,4): 128-reg budget, proven spill-free territory. Residency is
// register-bound at 2 blocks/CU in all spill-free configs (r2..r8), so LDS
// stays at the two-buffer 79KB layout and we optimize phase overlap instead.
__global__ __launch_bounds__(NTHREADS, 4) void fused_clf(
    const float* __restrict__ x, const float* __restrict__ Vw1f,
    const float* __restrict__ Vb1, const float* __restrict__ Vb2,
    const float* __restrict__ Vb3,
    const float* __restrict__ Ub1, const float* __restrict__ Ub2,
    const float* __restrict__ Ub3, const float* __restrict__ Uw3,
    const __bf16* __restrict__ ws,
    float* __restrict__ out)
{
  __shared__ alignas(16) __bf16 b1[RPB][LDA];   // a1 (lives through F)
  __shared__ alignas(16) __bf16 b2[RPB][LDA];   // u1 -> a2 -> t2'
  __shared__ union alignas(16) S3 {             // b3 live D..E; r4 live F..H
    __bf16 b3[RPB][72];                         // a3' = a3*(1-a3^2)
    float  r4[8][RPB][4];                       // grad_V per-wave partials
  } s3;
  __shared__ alignas(16) float red[RPB][4];
  __shared__ float utile[RPB];
  __shared__ float upart[4][RPB];               // U3-dot partials (no union)

  const int tid  = threadIdx.x;
  const int lane = tid & 63;
  const int wave = tid >> 6;       // 0..7
  const int quad = lane >> 4;
  const int l16  = lane & 15;
  const int row0 = blockIdx.x * RPB;

  // ---- x fragments (K=4 zero-padded to 32), B-operand of swapped MFMA ----
  v8bf xa[MT];
  #pragma unroll
  for (int m = 0; m < MT; m++){
    v8bf z;
    #pragma unroll
    for (int j = 0; j < 8; j++) z[j] = (__bf16)0.0f;
    if (quad == 0){
      float4 xv = ((const float4*)x)[row0 + m*16 + l16];
      z[0] = f2bf(xv.x); z[1] = f2bf(xv.y); z[2] = f2bf(xv.z); z[3] = f2bf(xv.w);
    }
    xa[m] = z;
  }

  // Swapped-operand MFMA: acc = mfma(Wfrag, ActFrag) computes C^T: lane
  // holds features f0..f0+3 (f0 = ntbase + quad*4) of batch row m*16+l16.

  // ---- layer-1 via MFMA (single K-step) ----
  auto layer1m = [&](const __bf16* __restrict__ Bw, const float* __restrict__ bv,
                     __bf16 (*dst)[LDA]){
    const v8bf* B = (const v8bf*)Bw;
    v8bf bf0 = B[(wave*2 + 0)*64 + lane];
    v8bf bf1 = B[(wave*2 + 1)*64 + lane];
    f32x4 acc[MT][2];
    #pragma unroll
    for (int m = 0; m < MT; m++){ f32x4 z={0.f,0.f,0.f,0.f}; acc[m][0]=z; acc[m][1]=z; }
    __builtin_amdgcn_s_setprio(1);
    #pragma unroll
    for (int m = 0; m < MT; m++){
      acc[m][0] = __builtin_amdgcn_mfma_f32_16x16x32_bf16(bf0, xa[m], acc[m][0], 0,0,0);
      acc[m][1] = __builtin_amdgcn_mfma_f32_16x16x32_bf16(bf1, xa[m], acc[m][1], 0,0,0);
    }
    __builtin_amdgcn_s_setprio(0);
    #pragma unroll
    for (int nt = 0; nt < 2; nt++){
      const int f0 = (wave*2 + nt)*16 + quad*4;
      f32x4 bvv = ((const f32x4*)bv)[f0 >> 2];
      #pragma unroll
      for (int m = 0; m < MT; m++){
        const int brow = m*16 + l16;
        uint2 pk;
        pk.x = pk2bf(tanhf_fast(acc[m][nt][0] + bvv[0]),
                     tanhf_fast(acc[m][nt][1] + bvv[1]));
        pk.y = pk2bf(tanhf_fast(acc[m][nt][2] + bvv[2]),
                     tanhf_fast(acc[m][nt][3] + bvv[3]));
        *(uint2*)&dst[brow][f0] = pk;
      }
    }
  };

  // ========== phase A: both layer-1s ====
  layer1m(ws + OFF_LU1, Ub1, b2);          // u1 -> b2
  layer1m(ws + OFF_LV1, Vb1, b1);          // a1 -> b1 (lives until F)
  __syncthreads();

  // ========== phase BC: U2+U3dot (waves 0-3) || V2 (waves 4-7) ====
  // U-waves: u2 = tanh(u1@Uw2^T+b), fold dot with Uw3 -> upart. Never stored.
  // V-waves: a2 = tanh(a1@Vw2^T+b) -> b2 (over u1; mid-barrier makes it safe).
  {
    const int grp = wave >> 2;     // 0 = U-net, 1 = V-net
    const int w4  = wave & 3;      // wave within group; owns n-tiles w4*4..+3
    const __bf16 (*A)[LDA] = grp ? b1 : b2;
    const v8bf* B = (const v8bf*)(ws + (grp ? OFF_B2T : OFF_U2T));
    f32x4 acc[MT][4];
    #pragma unroll
    for (int m = 0; m < MT; m++)
      #pragma unroll
      for (int j = 0; j < 4; j++){ f32x4 z={0.f,0.f,0.f,0.f}; acc[m][j]=z; }
    __builtin_amdgcn_s_setprio(1);
    #pragma unroll
    for (int kk = 0; kk < 8; kk++){
      v8bf a[MT];
      #pragma unroll
      for (int m = 0; m < MT; m++)
        a[m] = *(const v8bf*)&A[m*16 + l16][kk*32 + quad*8];
      #pragma unroll
      for (int j = 0; j < 4; j++){
        v8bf bf = B[(kk*16 + w4*4 + j)*64 + lane];
        #pragma unroll
        for (int m = 0; m < MT; m++)
          acc[m][j] = __builtin_amdgcn_mfma_f32_16x16x32_bf16(bf, a[m], acc[m][j], 0,0,0);
      }
    }
    __builtin_amdgcn_s_setprio(0);
    __syncthreads();   // U-waves done reading u1 (b2) before V writes a2 there
    if (grp == 0){
      float part[MT];
      #pragma unroll
      for (int m = 0; m < MT; m++) part[m] = 0.f;
      #pragma unroll
      for (int j = 0; j < 4; j++){
        const int f0 = (w4*4 + j)*16 + quad*4;
        f32x4 bvv = ((const f32x4*)Ub2)[f0 >> 2];
        f32x4 w3v = ((const f32x4*)Uw3)[f0 >> 2];
        #pragma unroll
        for (int m = 0; m < MT; m++)
          #pragma unroll
          for (int r = 0; r < 4; r++)
            part[m] = __builtin_fmaf(tanhf_fast(acc[m][j][r] + bvv[r]), w3v[r], part[m]);
      }
      #pragma unroll
      for (int m = 0; m < MT; m++){
        part[m] += __shfl_xor(part[m], 16);
        part[m] += __shfl_xor(part[m], 32);
        if (quad == 0) upart[w4][m*16 + l16] = part[m];
      }
    } else {
      #pragma unroll
      for (int j = 0; j < 4; j++){
        const int f0 = (w4*4 + j)*16 + quad*4;
        f32x4 bvv = ((const f32x4*)Vb2)[f0 >> 2];
        #pragma unroll
        for (int m = 0; m < MT; m++){
          uint2 pk;
          pk.x = pk2bf(tanhf_fast(acc[m][j][0] + bvv[0]),
                       tanhf_fast(acc[m][j][1] + bvv[1]));
          pk.y = pk2bf(tanhf_fast(acc[m][j][2] + bvv[2]),
                       tanhf_fast(acc[m][j][3] + bvv[3]));
          *(uint2*)&b2[m*16 + l16][f0] = pk;
        }
      }
    }
  }
  __syncthreads();

  // ========== phase D: z3 = a2 @ Vw3^T; fused V partials; a3' -> s3.b3 ====
  // wave 0 lanes finish u first (upart complete; no conflict with D writes)
  if (tid < RPB){
    float z = Ub3[0];
    #pragma unroll
    for (int w = 0; w < 4; w++) z += upart[w][tid];
    float u = tanhf_fast(z) * 20.0f;
    utile[tid] = u;
    out[row0 + tid] = u;
  }
  {
    const int mp = wave >> 2;     // 0..1
    const int nt = wave & 3;      // 0..3
    f32x4 acc[2];
    { f32x4 z={0.f,0.f,0.f,0.f}; acc[0]=z; acc[1]=z; }
    const v8bf* B = (const v8bf*)(ws + OFF_B3T);
    __builtin_amdgcn_s_setprio(1);
    #pragma unroll
    for (int kk = 0; kk < 8; kk++){
      v8bf bf = B[(kk*4 + nt)*64 + lane];
      #pragma unroll
      for (int m2 = 0; m2 < 2; m2++){
        v8bf a = *(const v8bf*)&b2[(mp*2 + m2)*16 + l16][kk*32 + quad*8];
        acc[m2] = __builtin_amdgcn_mfma_f32_16x16x32_bf16(bf, a, acc[m2], 0,0,0);
      }
    }
    __builtin_amdgcn_s_setprio(0);
    const int f0 = nt*16 + quad*4;
    f32x4 bvv = ((const f32x4*)Vb3)[f0 >> 2];
    #pragma unroll
    for (int m2 = 0; m2 < 2; m2++){
      const int brow = (mp*2 + m2)*16 + l16;
      float t0 = tanhf_fast(acc[m2][0] + bvv[0]);
      float t1 = tanhf_fast(acc[m2][1] + bvv[1]);
      float t2 = tanhf_fast(acc[m2][2] + bvv[2]);
      float t3 = tanhf_fast(acc[m2][3] + bvv[3]);
      float s0 = t0*t0, s1 = t1*t1, s2 = t2*t2, s3q = t3*t3;
      float sq = (s0 + s1) + (s2 + s3q);
      sq += __shfl_xor(sq, 16);
      sq += __shfl_xor(sq, 32);
      if (quad == 0) red[brow][nt] = sq;
      uint2 pk;
      pk.x = pk2bf(t0*(1.0f - s0), t1*(1.0f - s1));
      pk.y = pk2bf(t2*(1.0f - s2), t3*(1.0f - s3q));
      *(uint2*)&s3.b3[brow][f0] = pk;
    }
  }
  __syncthreads();

  // ========== phase E: t3 = a3' @ Vw3; t2' = t3*(1-a2^2) in place; emit V ==
  // a2 still in b2 (E's MFMA reads only s3.b3); lane reads its own slot
  // then overwrites it — lane-exclusive, no race.
  {
    f32x4 acc[MT][2];
    #pragma unroll
    for (int m = 0; m < MT; m++){ f32x4 z={0.f,0.f,0.f,0.f}; acc[m][0]=z; acc[m][1]=z; }
    const v8bf* B = (const v8bf*)(ws + OFF_B3);
    __builtin_amdgcn_s_setprio(1);
    #pragma unroll
    for (int kk = 0; kk < 2; kk++){
      v8bf a[MT];
      #pragma unroll
      for (int m = 0; m < MT; m++)
        a[m] = *(const v8bf*)&s3.b3[m*16 + l16][kk*32 + quad*8];
      #pragma unroll
      for (int nt = 0; nt < 2; nt++){
        v8bf bf = B[(kk*16 + wave*2 + nt)*64 + lane];
        #pragma unroll
        for (int m = 0; m < MT; m++)
          acc[m][nt] = __builtin_amdgcn_mfma_f32_16x16x32_bf16(bf, a[m], acc[m][nt], 0,0,0);
      }
    }
    __builtin_amdgcn_s_setprio(0);
    #pragma unroll
    for (int nt = 0; nt < 2; nt++){
      const int f0 = (wave*2 + nt)*16 + quad*4;
      #pragma unroll
      for (int m = 0; m < MT; m++){
        const int brow = m*16 + l16;
        uint2 old = *(const uint2*)&b2[brow][f0];      // a2 (in place)
        float a0 = bflo(old.x), a1 = bfhi(old.x);
        float c0 = bflo(old.y), c1 = bfhi(old.y);
        uint2 pk;
        pk.x = pk2bf(acc[m][nt][0] * (1.0f - a0*a0),
                     acc[m][nt][1] * (1.0f - a1*a1));
        pk.y = pk2bf(acc[m][nt][2] * (1.0f - c0*c0),
                     acc[m][nt][3] * (1.0f - c1*c1));
        *(uint2*)&b2[brow][f0] = pk;
      }
    }
    if (tid < RPB)
      out[BSZ + row0 + tid] = 0.5f * (red[tid][0] + red[tid][1] + red[tid][2] + red[tid][3]);
  }
  __syncthreads();

  // ========== phase F: s2' = (t2'@Vw2)*(1-a1^2), fused grad_V -> r4 ====
  // s2' never hits LDS; a1 re-read from b1 (still live); grad_V partial =
  // sum_f s2'[f]*Vw1[f][j] over the lane's 8 features, quad-reduced.
  {
    f32x4 acc[MT][2];
    #pragma unroll
    for (int m = 0; m < MT; m++){ f32x4 z={0.f,0.f,0.f,0.f}; acc[m][0]=z; acc[m][1]=z; }
    const v8bf* B = (const v8bf*)(ws + OFF_B2);
    __builtin_amdgcn_s_setprio(1);
    #pragma unroll
    for (int kk = 0; kk < 8; kk++){
      v8bf a[MT];
      #pragma unroll
      for (int m = 0; m < MT; m++)
        a[m] = *(const v8bf*)&b2[m*16 + l16][kk*32 + quad*8];
      #pragma unroll
      for (int nt = 0; nt < 2; nt++){
        v8bf bf = B[(kk*16 + wave*2 + nt)*64 + lane];
        #pragma unroll
        for (int m = 0; m < MT; m++)
          acc[m][nt] = __builtin_amdgcn_mfma_f32_16x16x32_bf16(bf, a[m], acc[m][nt], 0,0,0);
      }
    }
    __builtin_amdgcn_s_setprio(0);
    f32x4 gp[MT];
    #pragma unroll
    for (int m = 0; m < MT; m++){ f32x4 z={0.f,0.f,0.f,0.f}; gp[m]=z; }
    #pragma unroll
    for (int nt = 0; nt < 2; nt++){
      const int f0 = (wave*2 + nt)*16 + quad*4;
      f32x4 vw0 = ((const f32x4*)Vw1f)[f0 + 0];
      f32x4 vw1 = ((const f32x4*)Vw1f)[f0 + 1];
      f32x4 vw2 = ((const f32x4*)Vw1f)[f0 + 2];
      f32x4 vw3 = ((const f32x4*)Vw1f)[f0 + 3];
      #pragma unroll
      for (int m = 0; m < MT; m++){
        uint2 old = *(const uint2*)&b1[m*16 + l16][f0];   // a1 (still live)
        float a0 = bflo(old.x), a1 = bfhi(old.x);
        float c0 = bflo(old.y), c1 = bfhi(old.y);
        float s0 = acc[m][nt][0] * (1.0f - a0*a0);
        float s1 = acc[m][nt][1] * (1.0f - a1*a1);
        float s2 = acc[m][nt][2] * (1.0f - c0*c0);
        float s3v = acc[m][nt][3] * (1.0f - c1*c1);
        gp[m] += s0*vw0 + s1*vw1 + s2*vw2 + s3v*vw3;
      }
    }
    #pragma unroll
    for (int m = 0; m < MT; m++){
      #pragma unroll
      for (int j = 0; j < 4; j++){
        float v = gp[m][j];
        v += __shfl_xor(v, 16);
        v += __shfl_xor(v, 32);
        gp[m][j] = v;
      }
      if (quad == 0)
        *(f32x4*)&s3.r4[wave][m*16 + l16][0] = gp[m];
    }
  }
  __syncthreads();
  // ========== phase H: cross-wave sum ====
  if (tid < RPB*4){
    int b = tid >> 2, k2 = tid & 3;
    float s = 0.f;
    #pragma unroll
    for (int w = 0; w < 8; w++) s += s3.r4[w][b][k2];
    red[b][k2] = s;
  }
  __syncthreads();

  // ========== tail: dynamics + Vdot ====
  if (tid < RPB){
    float4 xv = ((const float4*)x)[row0 + tid];
    float th = xv.y, vv = xv.z, om = xv.w;
    float c, s;
    __sincosf(th, &s, &c);
    float rdc  = __builtin_amdgcn_rcpf(c - 24.7f);
    float rdc2 = __builtin_amdgcn_rcpf(c*c - 24.7f);
    float f2v = (c*(9.8f*s + 11.5f*vv) + 68.4f*vv - 1.2f*om*om*s) * rdc;
    float f3v = (-58.8f*vv*c - 243.5f*vv - s*(208.3f + om*om*c)) * rdc2;
    float g2v = (-1.8f*c - 10.9f) * rdc;
    float g3v = (9.3f*c + 38.6f) * rdc2;
    f32x4 rv = *(const f32x4*)&red[tid][0];
    float Lf = rv[0]*vv + rv[1]*om + rv[2]*f2v + rv[3]*f3v;
    float Lg = rv[2]*g2v + rv[3]*g3v;
    out[2*BSZ + row0 + tid] = Lf + Lg * utile[tid];
  }
}

extern "C" void kernel_launch(void* const* d_in, const int* in_sizes, int n_in,
                              void* d_out, int out_size, void* d_ws, size_t ws_size,
                              hipStream_t stream) {
  const float* x   = (const float*)d_in[0];
  const float* Vw1 = (const float*)d_in[1];
  const float* Vb1 = (const float*)d_in[2];
  const float* Vw2 = (const float*)d_in[3];
  const float* Vb2 = (const float*)d_in[4];
  const float* Vw3 = (const float*)d_in[5];
  const float* Vb3 = (const float*)d_in[6];
  const float* Uw1 = (const float*)d_in[7];
  const float* Ub1 = (const float*)d_in[8];
  const float* Uw2 = (const float*)d_in[9];
  const float* Ub2 = (const float*)d_in[10];
  const float* Uw3 = (const float*)d_in[11];
  const float* Ub3 = (const float*)d_in[12];
  __bf16* ws = (__bf16*)d_ws;
  float* out = (float*)d_out;

  hipLaunchKernelGGL(prep_weights, dim3((WS_ELEMS + 255) / 256), dim3(256), 0, stream,
                     Vw2, Uw2, Vw3, Vw1, Uw1, Uw3, ws);
  hipLaunchKernelGGL(fused_clf, dim3(BSZ / RPB), dim3(NTHREADS), 0, stream,
                     x, Vw1, Vb1, Vb2, Vb3, Ub1, Ub2, Ub3, Uw3, ws, out);
}

// Round 10
// 161.649 us; speedup vs baseline: 1.3648x; 1.0635x over previous
//
#include <hip/hip_runtime.h>
#include <hip/hip_bf16.h>

#define BSZ 131072

typedef __bf16 v8bf __attribute__((ext_vector_type(8)));
typedef float f32x4 __attribute__((ext_vector_type(4)));

constexpr int RPB = 64;        // rows per block
constexpr int NTHREADS = 512;  // 8 waves
constexpr int LDA = 264;       // 256 + 8 pad (528B rows, 16B aligned)

// d_ws layout (bf16 element offsets) — fragment-swizzled weights.
constexpr int OFF_B2T = 0;        // Vw2[n][k]   (256x256) NT=16
constexpr int OFF_U2T = 65536;    // Uw2[n][k]   (256x256) NT=16
constexpr int OFF_B2  = 131072;   // Vw2[k][n]   (256x256) NT=16
constexpr int OFF_B3T = 196608;   // Vw3[n][k]   (256x64)  NT=4
constexpr int OFF_B3  = 212992;   // Vw3[k][n]   (64x256)  NT=16
constexpr int OFF_U3  = 229376;   // Uw3[k] (unused by fused_clf now)
constexpr int OFF_GV  = 233472;   // Vw1[k][n] n<4 else 0  (256x16) NT=1
constexpr int OFF_LV1 = 237568;   // Vw1[n][k] k<4 else 0  (32x256)  NT=16
constexpr int OFF_LU1 = 245760;   // Uw1[n][k] k<4 else 0  (32x256)  NT=16
constexpr int WS_ELEMS = 253952;

// 3 VALU + 2 trans: exp2-form tanh. Exact at +-inf, no NaN.
__device__ __forceinline__ float tanhf_fast(float x){
  float e = __builtin_amdgcn_exp2f(x * 2.885390082f);   // exp(2x)
  return __builtin_fmaf(-2.0f, __builtin_amdgcn_rcpf(e + 1.0f), 1.0f);
}

__device__ __forceinline__ __bf16 f2bf(float f){
  unsigned u = __builtin_bit_cast(unsigned, f);
  u += 0x8000u;
  unsigned short h = (unsigned short)(u >> 16);
  return __builtin_bit_cast(__bf16, h);
}

// pack 2 f32 -> 2 bf16 in one instr (RNE)
__device__ __forceinline__ unsigned pk2bf(float lo, float hi){
  unsigned r;
  asm("v_cvt_pk_bf16_f32 %0, %1, %2" : "=v"(r) : "v"(lo), "v"(hi));
  return r;
}
__device__ __forceinline__ float bflo(unsigned u){ return __builtin_bit_cast(float, u << 16); }
__device__ __forceinline__ float bfhi(unsigned u){ return __builtin_bit_cast(float, u & 0xffff0000u); }

// ---- weight pre-swizzle: one thread per bf16 element of ws ----
__global__ void prep_weights(const float* __restrict__ Vw2,
                             const float* __restrict__ Uw2,
                             const float* __restrict__ Vw3,
                             const float* __restrict__ Vw1,
                             const float* __restrict__ Uw1,
                             const float* __restrict__ Uw3,
                             __bf16* __restrict__ ws){
  int e = blockIdx.x * 256 + threadIdx.x;
  if (e >= WS_ELEMS) return;
  int idx, NT, base, mode; const float* W;
  if      (e <  65536){ idx = e;          W = Vw2; mode = 0; NT = 16; base = OFF_B2T; }
  else if (e < 131072){ idx = e - 65536;  W = Uw2; mode = 0; NT = 16; base = OFF_U2T; }
  else if (e < 196608){ idx = e - 131072; W = Vw2; mode = 1; NT = 16; base = OFF_B2;  }
  else if (e < 212992){ idx = e - 196608; W = Vw3; mode = 0; NT = 4;  base = OFF_B3T; }
  else if (e < 229376){ idx = e - 212992; W = Vw3; mode = 1; NT = 16; base = OFF_B3;  }
  else if (e < 233472){ idx = e - 229376; W = Uw3; mode = 2; NT = 1;  base = OFF_U3;  }
  else if (e < 237568){ idx = e - 233472; W = Vw1; mode = 3; NT = 1;  base = OFF_GV;  }
  else if (e < 245760){ idx = e - 237568; W = Vw1; mode = 4; NT = 16; base = OFF_LV1; }
  else                { idx = e - 245760; W = Uw1; mode = 4; NT = 16; base = OFF_LU1; }
  int j = idx & 7, l = (idx >> 3) & 63, f = idx >> 9;
  int nt = f % NT, ks = f / NT;
  int k = ks * 32 + (l >> 4) * 8 + j;
  int n = nt * 16 + (l & 15);
  float v;
  if      (mode == 0) v = W[n * 256 + k];
  else if (mode == 1) v = W[k * 256 + n];
  else if (mode == 2) v = (n == 0) ? W[k] : 0.0f;
  else if (mode == 3) v = (n < 4)  ? W[k * 4 + n] : 0.0f;
  else                v = (k < 4)  ? W[n * 4 + k] : 0.0f;
  ws[base + idx] = f2bf(v);
}

__global__ __launch_bounds__(NTHREADS, 4) void fused_clf(
    const float* __restrict__ x,
    const float* __restrict__ Vb1, const float* __restrict__ Vb2,
    const float* __restrict__ Vb3,
    const float* __restrict__ Ub1, const float* __restrict__ Ub2,
    const float* __restrict__ Ub3, const float* __restrict__ Uw3,
    const __bf16* __restrict__ ws,
    float* __restrict__ out)
{
  __shared__ alignas(16) __bf16 b1[RPB][LDA];   // a1 -> s2'
  __shared__ alignas(16) __bf16 b2[RPB][LDA];   // u1 | a2 -> t2'
  __shared__ union alignas(16) S3 {             // r4 (U3/gradV partials) | b3
    __bf16 b3[RPB][72];                         // a3' = a3*(1-a3^2)
    float  r4[8][RPB][4];                       // per-wave reduction partials
  } s3;
  __shared__ alignas(16) float red[RPB][4];
  __shared__ float utile[RPB];

  const int tid  = threadIdx.x;
  const int lane = tid & 63;
  const int wave = tid >> 6;       // 0..7
  const int quad = lane >> 4;
  const int l16  = lane & 15;
  const int row0 = blockIdx.x * RPB;

  // ---- x fragments (K=4 zero-padded to 32), B-operand of swapped MFMA ----
  v8bf xa[4];
  #pragma unroll
  for (int m = 0; m < 4; m++){
    v8bf z;
    #pragma unroll
    for (int j = 0; j < 8; j++) z[j] = (__bf16)0.0f;
    if (quad == 0){
      float4 xv = ((const float4*)x)[row0 + m*16 + l16];
      z[0] = f2bf(xv.x); z[1] = f2bf(xv.y); z[2] = f2bf(xv.z); z[3] = f2bf(xv.w);
    }
    xa[m] = z;
  }

  // Swapped-operand MFMA: acc = mfma(Wfrag, ActFrag) computes C^T: lane
  // holds features f0..f0+3 (f0 = ntbase + quad*4) of batch row m*16+l16.

  // ---- layer-1 via MFMA (single K-step) ----
  auto layer1m = [&](const __bf16* __restrict__ Bw, const float* __restrict__ bv,
                     __bf16 (*dst)[LDA]){
    const v8bf* B = (const v8bf*)Bw;
    v8bf bf0 = B[(wave*2 + 0)*64 + lane];
    v8bf bf1 = B[(wave*2 + 1)*64 + lane];
    f32x4 acc[4][2];
    #pragma unroll
    for (int m = 0; m < 4; m++){ f32x4 z={0.f,0.f,0.f,0.f}; acc[m][0]=z; acc[m][1]=z; }
    __builtin_amdgcn_s_setprio(1);
    #pragma unroll
    for (int m = 0; m < 4; m++){
      acc[m][0] = __builtin_amdgcn_mfma_f32_16x16x32_bf16(bf0, xa[m], acc[m][0], 0,0,0);
      acc[m][1] = __builtin_amdgcn_mfma_f32_16x16x32_bf16(bf1, xa[m], acc[m][1], 0,0,0);
    }
    __builtin_amdgcn_s_setprio(0);
    #pragma unroll
    for (int nt = 0; nt < 2; nt++){
      const int f0 = (wave*2 + nt)*16 + quad*4;
      f32x4 bvv = ((const f32x4*)bv)[f0 >> 2];
      #pragma unroll
      for (int m = 0; m < 4; m++){
        const int brow = m*16 + l16;
        uint2 pk;
        pk.x = pk2bf(tanhf_fast(acc[m][nt][0] + bvv[0]),
                     tanhf_fast(acc[m][nt][1] + bvv[1]));
        pk.y = pk2bf(tanhf_fast(acc[m][nt][2] + bvv[2]),
                     tanhf_fast(acc[m][nt][3] + bvv[3]));
        *(uint2*)&dst[brow][f0] = pk;
      }
    }
  };

  // ---- (64x256)x(256x256): wave = 2 n-tiles, all 4 m-tiles ----
  auto gemm256 = [&](const __bf16 (*A)[LDA], const __bf16* __restrict__ Bw,
                     const float* __restrict__ bias, __bf16 (*dst)[LDA], int epi){
    f32x4 acc[4][2];
    #pragma unroll
    for (int m = 0; m < 4; m++){ f32x4 z={0.f,0.f,0.f,0.f}; acc[m][0]=z; acc[m][1]=z; }
    const v8bf* B = (const v8bf*)Bw;
    __builtin_amdgcn_s_setprio(1);
    #pragma unroll
    for (int kk = 0; kk < 8; kk++){
      v8bf a[4];
      #pragma unroll
      for (int m = 0; m < 4; m++)
        a[m] = *(const v8bf*)&A[m*16 + l16][kk*32 + quad*8];
      #pragma unroll
      for (int nt = 0; nt < 2; nt++){
        v8bf bf = B[(kk*16 + wave*2 + nt)*64 + lane];
        #pragma unroll
        for (int m = 0; m < 4; m++)
          acc[m][nt] = __builtin_amdgcn_mfma_f32_16x16x32_bf16(bf, a[m], acc[m][nt], 0,0,0);
      }
    }
    __builtin_amdgcn_s_setprio(0);
    #pragma unroll
    for (int nt = 0; nt < 2; nt++){
      const int f0 = (wave*2 + nt)*16 + quad*4;
      f32x4 bvv = {0.f,0.f,0.f,0.f};
      if (epi == 0) bvv = ((const f32x4*)bias)[f0 >> 2];
      #pragma unroll
      for (int m = 0; m < 4; m++){
        const int brow = m*16 + l16;
        uint2 pk;
        if (epi == 0){
          pk.x = pk2bf(tanhf_fast(acc[m][nt][0] + bvv[0]),
                       tanhf_fast(acc[m][nt][1] + bvv[1]));
          pk.y = pk2bf(tanhf_fast(acc[m][nt][2] + bvv[2]),
                       tanhf_fast(acc[m][nt][3] + bvv[3]));
        } else {
          uint2 old = *(const uint2*)&dst[brow][f0];
          float a0 = bflo(old.x), a1 = bfhi(old.x);
          float c0 = bflo(old.y), c1 = bfhi(old.y);
          pk.x = pk2bf(acc[m][nt][0] * (1.0f - a0*a0),
                       acc[m][nt][1] * (1.0f - a1*a1));
          pk.y = pk2bf(acc[m][nt][2] * (1.0f - c0*c0),
                       acc[m][nt][3] * (1.0f - c1*c1));
        }
        *(uint2*)&dst[brow][f0] = pk;
      }
    }
  };

  // ---- U2 with fused U3 dot: u2 never materialized. ----
  auto u2dot = [&](const __bf16 (*A)[LDA], const __bf16* __restrict__ Bw,
                   const float* __restrict__ bias, const float* __restrict__ w3){
    f32x4 acc[4][2];
    #pragma unroll
    for (int m = 0; m < 4; m++){ f32x4 z={0.f,0.f,0.f,0.f}; acc[m][0]=z; acc[m][1]=z; }
    const v8bf* B = (const v8bf*)Bw;
    __builtin_amdgcn_s_setprio(1);
    #pragma unroll
    for (int kk = 0; kk < 8; kk++){
      v8bf a[4];
      #pragma unroll
      for (int m = 0; m < 4; m++)
        a[m] = *(const v8bf*)&A[m*16 + l16][kk*32 + quad*8];
      #pragma unroll
      for (int nt = 0; nt < 2; nt++){
        v8bf bf = B[(kk*16 + wave*2 + nt)*64 + lane];
        #pragma unroll
        for (int m = 0; m < 4; m++)
          acc[m][nt] = __builtin_amdgcn_mfma_f32_16x16x32_bf16(bf, a[m], acc[m][nt], 0,0,0);
      }
    }
    __builtin_amdgcn_s_setprio(0);
    float part[4] = {0.f, 0.f, 0.f, 0.f};
    #pragma unroll
    for (int nt = 0; nt < 2; nt++){
      const int f0 = (wave*2 + nt)*16 + quad*4;
      f32x4 bvv = ((const f32x4*)bias)[f0 >> 2];
      f32x4 w3v = ((const f32x4*)w3)[f0 >> 2];
      #pragma unroll
      for (int m = 0; m < 4; m++)
        #pragma unroll
        for (int r = 0; r < 4; r++)
          part[m] = __builtin_fmaf(tanhf_fast(acc[m][nt][r] + bvv[r]), w3v[r], part[m]);
    }
    #pragma unroll
    for (int m = 0; m < 4; m++){
      part[m] += __shfl_xor(part[m], 16);
      part[m] += __shfl_xor(part[m], 32);
    }
    if (quad == 0){
      #pragma unroll
      for (int m = 0; m < 4; m++)
        s3.r4[wave][m*16 + l16][0] = part[m];
    }
  };

  // ---- N=16 MFMA reduction partial (grad_V): K split across 8 waves ----
  auto mfma_reduce4 = [&](const __bf16 (*A)[LDA], const __bf16* __restrict__ Bw){
    f32x4 acc[4];
    #pragma unroll
    for (int m = 0; m < 4; m++){ f32x4 z={0.f,0.f,0.f,0.f}; acc[m]=z; }
    const v8bf* B = (const v8bf*)Bw;
    v8bf bf = B[wave*64 + lane];           // frag ks = wave (NT=1)
    __builtin_amdgcn_s_setprio(1);
    #pragma unroll
    for (int m = 0; m < 4; m++){
      v8bf a = *(const v8bf*)&A[m*16 + l16][wave*32 + quad*8];
      acc[m] = __builtin_amdgcn_mfma_f32_16x16x32_bf16(bf, a, acc[m], 0,0,0);
    }
    __builtin_amdgcn_s_setprio(0);
    if (quad == 0){
      #pragma unroll
      for (int m = 0; m < 4; m++)
        *(f32x4*)&s3.r4[wave][m*16 + l16][0] = acc[m];
    }
  };

  // ========== phase A: both layer-1s (independent, no barrier between) ====
  layer1m(ws + OFF_LU1, Ub1, b2);          // u1 -> b2
  layer1m(ws + OFF_LV1, Vb1, b1);          // a1 -> b1
  __syncthreads();
  // ========== phase B: U2 + fused U3 dot -> r4 partials ====
  u2dot(b2, ws + OFF_U2T, Ub2, Uw3);
  __syncthreads();
  // ========== phase C: V2 (a2 -> b2); wave 0 finishes u ====
  gemm256(b1, ws + OFF_B2T, Vb2, b2, 0);
  if (tid < RPB){
    float z = Ub3[0];
    #pragma unroll
    for (int w = 0; w < 8; w++) z += s3.r4[w][tid][0];
    float u = tanhf_fast(z) * 20.0f;
    utile[tid] = u;
    out[row0 + tid] = u;
  }
  __syncthreads();

  // ========== phase D: z3 = a2 @ Vw3^T; fused V partials; a3' -> s3.b3 ====
  {
    const int mp = wave >> 2;     // 0..1
    const int nt = wave & 3;      // 0..3
    f32x4 acc[2];
    { f32x4 z={0.f,0.f,0.f,0.f}; acc[0]=z; acc[1]=z; }
    const v8bf* B = (const v8bf*)(ws + OFF_B3T);
    __builtin_amdgcn_s_setprio(1);
    #pragma unroll
    for (int kk = 0; kk < 8; kk++){
      v8bf bf = B[(kk*4 + nt)*64 + lane];
      #pragma unroll
      for (int m2 = 0; m2 < 2; m2++){
        v8bf a = *(const v8bf*)&b2[(mp*2 + m2)*16 + l16][kk*32 + quad*8];
        acc[m2] = __builtin_amdgcn_mfma_f32_16x16x32_bf16(bf, a, acc[m2], 0,0,0);
      }
    }
    __builtin_amdgcn_s_setprio(0);
    const int f0 = nt*16 + quad*4;
    f32x4 bvv = ((const f32x4*)Vb3)[f0 >> 2];
    #pragma unroll
    for (int m2 = 0; m2 < 2; m2++){
      const int brow = (mp*2 + m2)*16 + l16;
      float t0 = tanhf_fast(acc[m2][0] + bvv[0]);
      float t1 = tanhf_fast(acc[m2][1] + bvv[1]);
      float t2 = tanhf_fast(acc[m2][2] + bvv[2]);
      float t3 = tanhf_fast(acc[m2][3] + bvv[3]);
      float s0 = t0*t0, s1 = t1*t1, s2 = t2*t2, s3q = t3*t3;
      float sq = (s0 + s1) + (s2 + s3q);
      sq += __shfl_xor(sq, 16);
      sq += __shfl_xor(sq, 32);
      if (quad == 0) red[brow][nt] = sq;
      uint2 pk;
      pk.x = pk2bf(t0*(1.0f - s0), t1*(1.0f - s1));
      pk.y = pk2bf(t2*(1.0f - s2), t3*(1.0f - s3q));
      *(uint2*)&s3.b3[brow][f0] = pk;
    }
  }
  __syncthreads();

  // ========== phase E: t3 = a3' @ Vw3; t2' = t3*(1-a2^2) in place; emit V ==
  {
    f32x4 acc[4][2];
    #pragma unroll
    for (int m = 0; m < 4; m++){ f32x4 z={0.f,0.f,0.f,0.f}; acc[m][0]=z; acc[m][1]=z; }
    const v8bf* B = (const v8bf*)(ws + OFF_B3);
    __builtin_amdgcn_s_setprio(1);
    #pragma unroll
    for (int kk = 0; kk < 2; kk++){
      v8bf a[4];
      #pragma unroll
      for (int m = 0; m < 4; m++)
        a[m] = *(const v8bf*)&s3.b3[m*16 + l16][kk*32 + quad*8];
      #pragma unroll
      for (int nt = 0; nt < 2; nt++){
        v8bf bf = B[(kk*16 + wave*2 + nt)*64 + lane];
        #pragma unroll
        for (int m = 0; m < 4; m++)
          acc[m][nt] = __builtin_amdgcn_mfma_f32_16x16x32_bf16(bf, a[m], acc[m][nt], 0,0,0);
      }
    }
    __builtin_amdgcn_s_setprio(0);
    #pragma unroll
    for (int nt = 0; nt < 2; nt++){
      const int f0 = (wave*2 + nt)*16 + quad*4;
      #pragma unroll
      for (int m = 0; m < 4; m++){
        const int brow = m*16 + l16;
        uint2 old = *(const uint2*)&b2[brow][f0];
        float a0 = bflo(old.x), a1 = bfhi(old.x);
        float c0 = bflo(old.y), c1 = bfhi(old.y);
        uint2 pk;
        pk.x = pk2bf(acc[m][nt][0] * (1.0f - a0*a0),
                     acc[m][nt][1] * (1.0f - a1*a1));
        pk.y = pk2bf(acc[m][nt][2] * (1.0f - c0*c0),
                     acc[m][nt][3] * (1.0f - c1*c1));
        *(uint2*)&b2[brow][f0] = pk;
      }
    }
    if (tid < RPB)
      out[BSZ + row0 + tid] = 0.5f * (red[tid][0] + red[tid][1] + red[tid][2] + red[tid][3]);
  }
  __syncthreads();

  // ========== phase F: s2' = (t2'@Vw2)*(1-a1^2) -> b1 ====
  gemm256(b2, ws + OFF_B2, nullptr, b1, 1);
  __syncthreads();
  // ========== phase G: grad_V partials -> r4 (b3 dead) ====
  mfma_reduce4(b1, ws + OFF_GV);
  __syncthreads();
  // ========== phase H: cross-wave sum ====
  if (tid < 256){
    int b = tid >> 2, k2 = tid & 3;
    float s = 0.f;
    #pragma unroll
    for (int w = 0; w < 8; w++) s += s3.r4[w][b][k2];
    red[b][k2] = s;
  }
  __syncthreads();

  // ========== tail: dynamics + Vdot ====
  if (tid < RPB){
    float4 xv = ((const float4*)x)[row0 + tid];
    float th = xv.y, vv = xv.z, om = xv.w;
    float c, s;
    __sincosf(th, &s, &c);
    float rdc  = __builtin_amdgcn_rcpf(c - 24.7f);
    float rdc2 = __builtin_amdgcn_rcpf(c*c - 24.7f);
    float f2v = (c*(9.8f*s + 11.5f*vv) + 68.4f*vv - 1.2f*om*om*s) * rdc;
    float f3v = (-58.8f*vv*c - 243.5f*vv - s*(208.3f + om*om*c)) * rdc2;
    float g2v = (-1.8f*c - 10.9f) * rdc;
    float g3v = (9.3f*c + 38.6f) * rdc2;
    f32x4 rv = *(const f32x4*)&red[tid][0];
    float Lf = rv[0]*vv + rv[1]*om + rv[2]*f2v + rv[3]*f3v;
    float Lg = rv[2]*g2v + rv[3]*g3v;
    out[2*BSZ + row0 + tid] = Lf + Lg * utile[tid];
  }
}

extern "C" void kernel_launch(void* const* d_in, const int* in_sizes, int n_in,
                              void* d_out, int out_size, void* d_ws, size_t ws_size,
                              hipStream_t stream) {
  const float* x   = (const float*)d_in[0];
  const float* Vw1 = (const float*)d_in[1];
  const float* Vb1 = (const float*)d_in[2];
  const float* Vw2 = (const float*)d_in[3];
  const float* Vb2 = (const float*)d_in[4];
  const float* Vw3 = (const float*)d_in[5];
  const float* Vb3 = (const float*)d_in[6];
  const float* Uw1 = (const float*)d_in[7];
  const float* Ub1 = (const float*)d_in[8];
  const float* Uw2 = (const float*)d_in[9];
  const float* Ub2 = (const float*)d_in[10];
  const float* Uw3 = (const float*)d_in[11];
  const float* Ub3 = (const float*)d_in[12];
  __bf16* ws = (__bf16*)d_ws;
  float* out = (float*)d_out;

  hipLaunchKernelGGL(prep_weights, dim3((WS_ELEMS + 255) / 256), dim3(256), 0, stream,
                     Vw2, Uw2, Vw3, Vw1, Uw1, Uw3, ws);
  hipLaunchKernelGGL(fused_clf, dim3(BSZ / RPB), dim3(NTHREADS), 0, stream,
                     x, Vb1, Vb2, Vb3, Ub1, Ub2, Ub3, Uw3, ws, out);
}